// Round 5
// baseline (241.882 us; speedup 1.0000x reference)
//
#include <hip/hip_runtime.h>

// Problem constants (match reference file).
#define M_ROWS 200000
#define D_DIM  256
#define NB     1024          // blocks
#define TPB    256           // threads per block (4 waves) — measured-best (round 2)
#define WPB    (TPB / 64)    // waves per block
#define TOTAL_WAVES (NB * WPB)

// Fused kernel: streaming phase identical to the round-2 pass1 (measured
// 74 µs wall, delivery-pipe-saturated at ~6.2 TB/s). After writing its
// 256-float partial (column-major), each block does __threadfence() +
// atomicAdd(counter); the last-arriving block re-reads all partials in a
// fixed order and writes the final output — saving the second kernel
// launch and its latency-bound 1 MB pass.
__global__ __launch_bounds__(TPB) void iv_fused(
    const float* __restrict__ u,
    const float4* __restrict__ keys4,
    const float4* __restrict__ values4,
    float* __restrict__ partial,   // layout: partial[col * NB + block]
    int* __restrict__ counter,     // zeroed by hipMemsetAsync each call
    float* __restrict__ out)       // 512 floats: [u ; u_]
{
    const int lane  = threadIdx.x & 63;
    const int wid   = threadIdx.x >> 6;
    const int gwave = blockIdx.x * WPB + wid;

    // u fragment for this lane (D=256 = 64 lanes * 4 floats)
    const float4 u4 = ((const float4*)u)[lane];

    float4 acc = make_float4(0.f, 0.f, 0.f, 0.f);

    for (int row = gwave; row < M_ROWS; row += TOTAL_WAVES) {
        const float4 k4 = keys4[row * 64 + lane];
        float p = k4.x * u4.x + k4.y * u4.y + k4.z * u4.z + k4.w * u4.w;
        #pragma unroll
        for (int m = 32; m >= 1; m >>= 1)
            p += __shfl_xor(p, m, 64);
        const float r = __expf(p);
        const float4 v4 = values4[row * 64 + lane];
        acc.x += r * v4.x;
        acc.y += r * v4.y;
        acc.z += r * v4.z;
        acc.w += r * v4.w;
    }

    // Block reduction across the 4 waves. Lane l of wave w holds cols 4l..4l+3.
    __shared__ float lds[WPB][D_DIM];
    *(float4*)&lds[wid][lane * 4] = acc;
    __syncthreads();

    const int t = threadIdx.x;   // t == column index
    {
        float s = lds[0][t] + lds[1][t] + lds[2][t] + lds[3][t];
        // Column-major so the final block reads each column contiguously.
        partial[t * NB + blockIdx.x] = s;
    }

    // --- last-block-done final reduction ---
    __threadfence();  // make partial[] visible device-wide (cross-XCD)
    __shared__ int is_last;
    if (t == 0) {
        const int old = atomicAdd(counter, 1);
        is_last = (old == NB - 1);
    }
    __syncthreads();

    if (is_last) {
        __threadfence();  // acquire: observe all blocks' partial writes
        // Thread t sums its column's NB partials (contiguous, fixed order
        // -> deterministic). float4 loads, 4 independent accumulators.
        const float4* p4 = (const float4*)(partial + t * NB);
        float4 a = make_float4(0.f, 0.f, 0.f, 0.f);
        #pragma unroll 8
        for (int i = 0; i < NB / 4; ++i) {
            const float4 q = p4[i];
            a.x += q.x; a.y += q.y; a.z += q.z; a.w += q.w;
        }
        out[D_DIM + t] = (a.x + a.y) + (a.z + a.w);
        out[t] = u[t];
    }
}

extern "C" void kernel_launch(void* const* d_in, const int* in_sizes, int n_in,
                              void* d_out, int out_size, void* d_ws, size_t ws_size,
                              hipStream_t stream) {
    const float* u      = (const float*)d_in[0];   // (256,)
    const float* keys   = (const float*)d_in[1];   // (200000, 256)
    const float* values = (const float*)d_in[2];   // (200000, 256)
    float* out = (float*)d_out;                    // 512 floats: [u ; u_]

    float* partial = (float*)d_ws;                 // NB*256*4 = 1 MB
    int* counter = (int*)((char*)d_ws + NB * D_DIM * sizeof(float));

    // Counter must be 0 at the start of every call (graph-capturable).
    hipMemsetAsync(counter, 0, sizeof(int), stream);

    iv_fused<<<NB, TPB, 0, stream>>>(u, (const float4*)keys,
                                     (const float4*)values,
                                     partial, counter, out);
}

// Round 6
// 75.236 us; speedup vs baseline: 3.2150x; 3.2150x over previous
//
#include <hip/hip_runtime.h>

// Problem constants (match reference file).
#define M_ROWS 200000
#define D_DIM  256
#define NB     1024          // pass-1 blocks
#define TPB    256           // threads per block (4 waves) — measured best (R2: 74.0 us)
#define WPB    (TPB / 64)    // waves per block
#define TOTAL_WAVES (NB * WPB)

// Pass 1: each wave processes whole rows. Lane l holds u[4l..4l+3] in regs.
// Per row: coalesced float4 load of keys row, wave-reduce dot, exp, then
// accumulate r * values row into per-lane float4 accumulator.
// Block-reduce 4 waves via LDS; write 256-float partial column-major into ws.
//
// R3/R4 (TPB=512, ROWS=2/4 ILP): 78 us — slower. R5 (fused last-block-done
// reduction): 242 us — uncoalesced single-block tail + 1024 threadfences.
// This exact config measured 74.0 us = 410 MB @ ~6.2 TB/s delivered (~98%
// of the measured float4-stream ceiling) + ~8 us pass-2/launch overhead.
__global__ __launch_bounds__(TPB) void iv_pass1(
    const float* __restrict__ u,
    const float4* __restrict__ keys4,
    const float4* __restrict__ values4,
    float* __restrict__ partial)   // layout: partial[col * NB + block]
{
    const int lane  = threadIdx.x & 63;
    const int wid   = threadIdx.x >> 6;
    const int gwave = blockIdx.x * WPB + wid;

    // u fragment for this lane (D=256 = 64 lanes * 4 floats)
    const float4 u4 = ((const float4*)u)[lane];

    float4 acc = make_float4(0.f, 0.f, 0.f, 0.f);

    for (int row = gwave; row < M_ROWS; row += TOTAL_WAVES) {
        const float4 k4 = keys4[row * 64 + lane];
        float p = k4.x * u4.x + k4.y * u4.y + k4.z * u4.z + k4.w * u4.w;
        // 64-lane butterfly reduction -> every lane has the full dot product
        #pragma unroll
        for (int m = 32; m >= 1; m >>= 1)
            p += __shfl_xor(p, m, 64);
        const float r = __expf(p);
        const float4 v4 = values4[row * 64 + lane];
        acc.x += r * v4.x;
        acc.y += r * v4.y;
        acc.z += r * v4.z;
        acc.w += r * v4.w;
    }

    // Block reduction across the 4 waves. Lane l of wave w holds cols 4l..4l+3.
    __shared__ float lds[WPB][D_DIM];
    *(float4*)&lds[wid][lane * 4] = acc;
    __syncthreads();

    const int t = threadIdx.x;   // t == column index
    float s = lds[0][t] + lds[1][t] + lds[2][t] + lds[3][t];
    // Column-major so pass 2 reads each column's partials contiguously.
    partial[t * NB + blockIdx.x] = s;
}

// Pass 2: block c sums its 1024 partials (contiguous across threads ->
// coalesced, L2/L3-resident), writes out[256+c]; also out[c] = u[c].
__global__ __launch_bounds__(256) void iv_pass2(
    const float* __restrict__ partial,
    const float* __restrict__ u,
    float* __restrict__ out)
{
    const int c = blockIdx.x;
    const int t = threadIdx.x;

    float s = 0.f;
    #pragma unroll
    for (int i = 0; i < NB / 256; ++i)
        s += partial[c * NB + i * 256 + t];

    #pragma unroll
    for (int m = 32; m >= 1; m >>= 1)
        s += __shfl_xor(s, m, 64);

    __shared__ float lds[256 / 64];
    if ((t & 63) == 0) lds[t >> 6] = s;
    __syncthreads();

    if (t == 0) {
        out[D_DIM + c] = lds[0] + lds[1] + lds[2] + lds[3];
        out[c] = u[c];
    }
}

extern "C" void kernel_launch(void* const* d_in, const int* in_sizes, int n_in,
                              void* d_out, int out_size, void* d_ws, size_t ws_size,
                              hipStream_t stream) {
    const float* u      = (const float*)d_in[0];   // (256,)
    const float* keys   = (const float*)d_in[1];   // (200000, 256)
    const float* values = (const float*)d_in[2];   // (200000, 256)
    float* out = (float*)d_out;                    // 512 floats: [u ; u_]
    float* partial = (float*)d_ws;                 // needs NB*256*4 = 1 MB

    iv_pass1<<<NB, TPB, 0, stream>>>(u, (const float4*)keys,
                                     (const float4*)values, partial);
    iv_pass2<<<D_DIM, 256, 0, stream>>>(partial, u, out);
}

// Round 9
// 72.034 us; speedup vs baseline: 3.3579x; 1.0445x over previous
//
#include <hip/hip_runtime.h>

// Problem constants (match reference file).
#define M_ROWS 200000
#define D_DIM  256
#define NB     256           // pass-1 blocks
#define TPB    1024          // threads per block (16 waves)
#define WPB    (TPB / 64)    // waves per block
#define TOTAL_WAVES (NB * WPB)   // 4096 — identical to measured-best R2 config

// Pass 1: streaming loop bit-identical to R2/R6 (74-75 us wall, delivered
// BW ~6.2 TB/s = 98% of measured float4-stream ceiling). Changes vs R6 are
// tail-only: 16 waves/block so the partial is [NB=256][256] row-major and
// the store is one coalesced 1 KB line per block (R6's column-major store
// scattered 256 cachelines/block -> WRITE_SIZE 8.2 MB for a 1 MB buffer).
__global__ __launch_bounds__(TPB) void iv_pass1(
    const float* __restrict__ u,
    const float4* __restrict__ keys4,
    const float4* __restrict__ values4,
    float* __restrict__ partial)   // layout: partial[block * D_DIM + col]
{
    const int lane  = threadIdx.x & 63;
    const int wid   = threadIdx.x >> 6;
    const int gwave = blockIdx.x * WPB + wid;

    // u fragment for this lane (D=256 = 64 lanes * 4 floats)
    const float4 u4 = ((const float4*)u)[lane];

    float4 acc = make_float4(0.f, 0.f, 0.f, 0.f);

    for (int row = gwave; row < M_ROWS; row += TOTAL_WAVES) {
        const float4 k4 = keys4[row * 64 + lane];
        float p = k4.x * u4.x + k4.y * u4.y + k4.z * u4.z + k4.w * u4.w;
        // 64-lane butterfly reduction -> every lane has the full dot product
        #pragma unroll
        for (int m = 32; m >= 1; m >>= 1)
            p += __shfl_xor(p, m, 64);
        const float r = __expf(p);
        const float4 v4 = values4[row * 64 + lane];
        acc.x += r * v4.x;
        acc.y += r * v4.y;
        acc.z += r * v4.z;
        acc.w += r * v4.w;
    }

    // Block reduction across 16 waves. Lane l of wave w holds cols 4l..4l+3.
    __shared__ float lds[WPB][D_DIM];   // 16 KB
    *(float4*)&lds[wid][lane * 4] = acc;
    __syncthreads();

    const int t = threadIdx.x;   // first 256 threads: t == column index
    if (t < D_DIM) {
        float s = 0.f;
        #pragma unroll
        for (int w = 0; w < WPB; ++w) s += lds[w][t];
        // Row-major: one coalesced 1 KB store per block.
        partial[blockIdx.x * D_DIM + t] = s;
    }
}

// Pass 2: block c sums column c's 256 partials (one 4 B load per thread,
// stride 1 KB, all L2-resident), writes out[256+c]; also out[c] = u[c].
__global__ __launch_bounds__(256) void iv_pass2(
    const float* __restrict__ partial,
    const float* __restrict__ u,
    float* __restrict__ out)
{
    const int c = blockIdx.x;
    const int t = threadIdx.x;   // t == partial row index

    float s = partial[t * D_DIM + c];

    #pragma unroll
    for (int m = 32; m >= 1; m >>= 1)
        s += __shfl_xor(s, m, 64);

    __shared__ float lds[256 / 64];
    if ((t & 63) == 0) lds[t >> 6] = s;
    __syncthreads();

    if (t == 0) {
        out[D_DIM + c] = lds[0] + lds[1] + lds[2] + lds[3];
        out[c] = u[c];
    }
}

extern "C" void kernel_launch(void* const* d_in, const int* in_sizes, int n_in,
                              void* d_out, int out_size, void* d_ws, size_t ws_size,
                              hipStream_t stream) {
    const float* u      = (const float*)d_in[0];   // (256,)
    const float* keys   = (const float*)d_in[1];   // (200000, 256)
    const float* values = (const float*)d_in[2];   // (200000, 256)
    float* out = (float*)d_out;                    // 512 floats: [u ; u_]
    float* partial = (float*)d_ws;                 // needs NB*256*4 = 256 KB

    iv_pass1<<<NB, TPB, 0, stream>>>(u, (const float4*)keys,
                                     (const float4*)values, partial);
    iv_pass2<<<D_DIM, 256, 0, stream>>>(partial, u, out);
}